// Round 2
// baseline (31485.464 us; speedup 1.0000x reference)
//
#include <hip/hip_runtime.h>
#include <hip/hip_bf16.h>
#include <stdint.h>

// Problem constants: B=64, S=512, D=1024, H=1024, O=1024
#define BB   64
#define SS   512
#define DD   1024
#define HH   1024
#define TH3  3072   // 3*H

#define BM 128
#define BN 128
#define BK 8

__device__ __forceinline__ float bf2f(unsigned short u) {
    union { uint32_t i; float f; } v;
    v.i = ((uint32_t)u) << 16;
    return v.f;
}

// ---------------------------------------------------------------------------
// Gx chunk GEMM: for s in [s0, s0+CH), all b:
//   Gx[(s-s0)*B + b, :] = x[b, s, :] @ Wg[:D, :] + bg
// A-row gather does the [B,S]->[CH,B] remap; output is contiguous.
// ---------------------------------------------------------------------------
__global__ __launch_bounds__(256) void gx_gemm(
    const float* __restrict__ x, const float* __restrict__ Wg,
    const float* __restrict__ bg, float* __restrict__ Gx, int s0)
{
    __shared__ float As[BK][BM + 4];
    __shared__ float Bs[BK][BN + 4];

    const int tid = threadIdx.x;
    const int bx = blockIdx.x;   // N tile (3H)
    const int by = blockIdx.y;   // M tile (CH*B)

    const int arow = tid >> 1;          // 0..127
    const int acol = (tid & 1) * 4;     // 0 or 4
    const int brow = tid >> 5;          // 0..7
    const int bcol = (tid & 31) * 4;    // 0..124

    const int tx8 = (tid & 15) * 8;
    const int ty8 = (tid >> 4) * 8;

    float acc[8][8];
#pragma unroll
    for (int i = 0; i < 8; ++i)
#pragma unroll
        for (int j = 0; j < 8; ++j) acc[i][j] = 0.f;

    const int m = by * BM + arow;             // chunk-local row: sl*B + b
    const int b = m & (BB - 1);
    const int sl = m >> 6;
    const float* Aptr = x + ((size_t)b * SS + s0 + sl) * DD + acol;
    const float* Bptr = Wg + (size_t)brow * TH3 + bx * BN + bcol;

    for (int k0 = 0; k0 < DD; k0 += BK) {
        float4 av = *(const float4*)Aptr;
        float4 bv = *(const float4*)Bptr;
        As[acol + 0][arow] = av.x;
        As[acol + 1][arow] = av.y;
        As[acol + 2][arow] = av.z;
        As[acol + 3][arow] = av.w;
        *(float4*)&Bs[brow][bcol] = bv;
        __syncthreads();

#pragma unroll
        for (int k = 0; k < BK; ++k) {
            float a[8], bvv[8];
            *(float4*)&a[0] = *(const float4*)&As[k][ty8];
            *(float4*)&a[4] = *(const float4*)&As[k][ty8 + 4];
            *(float4*)&bvv[0] = *(const float4*)&Bs[k][tx8];
            *(float4*)&bvv[4] = *(const float4*)&Bs[k][tx8 + 4];
#pragma unroll
            for (int i = 0; i < 8; ++i)
#pragma unroll
                for (int j = 0; j < 8; ++j)
                    acc[i][j] += a[i] * bvv[j];
        }
        __syncthreads();
        Aptr += BK;
        Bptr += (size_t)BK * TH3;
    }

    float bv8[8];
#pragma unroll
    for (int j = 0; j < 8; ++j) bv8[j] = bg[bx * BN + tx8 + j];

#pragma unroll
    for (int i = 0; i < 8; ++i) {
        float* cptr = Gx + (size_t)(by * BM + ty8 + i) * TH3 + bx * BN + tx8;
        float4 v0, v1;
        v0.x = acc[i][0] + bv8[0];
        v0.y = acc[i][1] + bv8[1];
        v0.z = acc[i][2] + bv8[2];
        v0.w = acc[i][3] + bv8[3];
        v1.x = acc[i][4] + bv8[4];
        v1.y = acc[i][5] + bv8[5];
        v1.z = acc[i][6] + bv8[6];
        v1.w = acc[i][7] + bv8[7];
        *(float4*)cptr = v0;
        *(float4*)(cptr + 4) = v1;
    }
}

// ---------------------------------------------------------------------------
// Output GEMM: out[M=B*S, O] = hs_bf16[M, H] @ Wc[H, O] + bc
// ---------------------------------------------------------------------------
__global__ __launch_bounds__(256) void out_gemm(
    const __hip_bfloat16* __restrict__ A, const float* __restrict__ Bm,
    const float* __restrict__ bias, float* __restrict__ C)
{
    __shared__ float As[BK][BM + 4];
    __shared__ float Bs[BK][BN + 4];

    const int tid = threadIdx.x;
    const int bx = blockIdx.x;
    const int by = blockIdx.y;

    const int arow = tid >> 1;
    const int acol = (tid & 1) * 4;
    const int brow = tid >> 5;
    const int bcol = (tid & 31) * 4;

    const int tx8 = (tid & 15) * 8;
    const int ty8 = (tid >> 4) * 8;

    float acc[8][8];
#pragma unroll
    for (int i = 0; i < 8; ++i)
#pragma unroll
        for (int j = 0; j < 8; ++j) acc[i][j] = 0.f;

    const unsigned short* Aptr =
        (const unsigned short*)A + (size_t)(by * BM + arow) * HH + acol;
    const float* Bptr = Bm + (size_t)brow * HH + bx * BN + bcol;

    for (int k0 = 0; k0 < HH; k0 += BK) {
        ushort4 au = *(const ushort4*)Aptr;
        float4 bv = *(const float4*)Bptr;
        As[acol + 0][arow] = bf2f(au.x);
        As[acol + 1][arow] = bf2f(au.y);
        As[acol + 2][arow] = bf2f(au.z);
        As[acol + 3][arow] = bf2f(au.w);
        *(float4*)&Bs[brow][bcol] = bv;
        __syncthreads();

#pragma unroll
        for (int k = 0; k < BK; ++k) {
            float a[8], bvv[8];
            *(float4*)&a[0] = *(const float4*)&As[k][ty8];
            *(float4*)&a[4] = *(const float4*)&As[k][ty8 + 4];
            *(float4*)&bvv[0] = *(const float4*)&Bs[k][tx8];
            *(float4*)&bvv[4] = *(const float4*)&Bs[k][tx8 + 4];
#pragma unroll
            for (int i = 0; i < 8; ++i)
#pragma unroll
                for (int j = 0; j < 8; ++j)
                    acc[i][j] += a[i] * bvv[j];
        }
        __syncthreads();
        Aptr += BK;
        Bptr += (size_t)BK * HH;
    }

    float bv8[8];
#pragma unroll
    for (int j = 0; j < 8; ++j) bv8[j] = bias[bx * BN + tx8 + j];

#pragma unroll
    for (int i = 0; i < 8; ++i) {
        float* cptr = C + (size_t)(by * BM + ty8 + i) * HH + bx * BN + tx8;
        float4 v0, v1;
        v0.x = acc[i][0] + bv8[0];
        v0.y = acc[i][1] + bv8[1];
        v0.z = acc[i][2] + bv8[2];
        v0.w = acc[i][3] + bv8[3];
        v1.x = acc[i][4] + bv8[4];
        v1.y = acc[i][5] + bv8[5];
        v1.z = acc[i][6] + bv8[6];
        v1.w = acc[i][7] + bv8[7];
        *(float4*)cptr = v0;
        *(float4*)(cptr + 4) = v1;
    }
}

// ---------------------------------------------------------------------------
// One GRU step. Grid = H/16 = 64 blocks, 256 threads.
// ---------------------------------------------------------------------------
#define NT 16
#define KT 32

__global__ __launch_bounds__(256) void gru_step(
    const float* __restrict__ Wg,      // full [D+H, 3H]; rows D.. used
    const float* __restrict__ gx,      // chunk Gx + tt*B*3H, layout [B, 3H]
    const float* __restrict__ h_cur,   // [B, H] fp32
    float* __restrict__ h_next,        // [B, H] fp32
    __hip_bfloat16* __restrict__ hs,   // [B, S, H] bf16
    int t)
{
    __shared__ float Hs[KT][BB + 4];
    __shared__ float Ws[KT][3 * NT];

    const int tid = threadIdx.x;
    const int j0 = blockIdx.x * NT;
    const int tx = tid & 15;
    const int ty = tid >> 4;

    const float* Wh = Wg + (size_t)DD * TH3;

    const int lr = tid >> 2;          // 0..63
    const int lk = (tid & 3) * 8;     // 0,8,16,24

    float acc[4][3];
#pragma unroll
    for (int i = 0; i < 4; ++i)
#pragma unroll
        for (int g = 0; g < 3; ++g) acc[i][g] = 0.f;

    for (int k0 = 0; k0 < HH; k0 += KT) {
        float4 hv0 = *(const float4*)&h_cur[lr * HH + k0 + lk];
        float4 hv1 = *(const float4*)&h_cur[lr * HH + k0 + lk + 4];
        Hs[lk + 0][lr] = hv0.x;
        Hs[lk + 1][lr] = hv0.y;
        Hs[lk + 2][lr] = hv0.z;
        Hs[lk + 3][lr] = hv0.w;
        Hs[lk + 4][lr] = hv1.x;
        Hs[lk + 5][lr] = hv1.y;
        Hs[lk + 6][lr] = hv1.z;
        Hs[lk + 7][lr] = hv1.w;
#pragma unroll
        for (int i = 0; i < 6; ++i) {
            int lin = tid + i * 256;       // 0..1535 = 32k x 48c
            int k = lin / 48;
            int c = lin % 48;
            int g = c >> 4, cc = c & 15;
            Ws[k][c] = Wh[(size_t)(k0 + k) * TH3 + g * HH + j0 + cc];
        }
        __syncthreads();

#pragma unroll
        for (int k = 0; k < KT; ++k) {
            float4 hv = *(const float4*)&Hs[k][ty * 4];
            float w0 = Ws[k][tx];
            float w1 = Ws[k][16 + tx];
            float w2 = Ws[k][32 + tx];
            acc[0][0] += hv.x * w0; acc[1][0] += hv.y * w0;
            acc[2][0] += hv.z * w0; acc[3][0] += hv.w * w0;
            acc[0][1] += hv.x * w1; acc[1][1] += hv.y * w1;
            acc[2][1] += hv.z * w1; acc[3][1] += hv.w * w1;
            acc[0][2] += hv.x * w2; acc[1][2] += hv.y * w2;
            acc[2][2] += hv.z * w2; acc[3][2] += hv.w * w2;
        }
        __syncthreads();
    }

    const int col = j0 + tx;
#pragma unroll
    for (int i = 0; i < 4; ++i) {
        int m = ty * 4 + i;
        float rg = acc[i][0] + gx[m * TH3 + col];
        float zg = acc[i][1] + gx[m * TH3 + HH + col];
        float ng = acc[i][2] + gx[m * TH3 + 2 * HH + col];
        float hold = h_cur[m * HH + col];
        float r = 1.f / (1.f + __expf(-rg));
        float z = 1.f / (1.f + __expf(-zg));
        float narg = ng + r * hold;
        float n = 1.f - 2.f / (1.f + __expf(2.f * narg));   // tanh
        float hn = (1.f - z) * n + z * hold;
        h_next[m * HH + col] = hn;
        hs[((size_t)m * SS + t) * HH + col] = __float2bfloat16(hn);
    }
}

// ---------------------------------------------------------------------------
extern "C" void kernel_launch(void* const* d_in, const int* in_sizes, int n_in,
                              void* d_out, int out_size, void* d_ws, size_t ws_size,
                              hipStream_t stream) {
    const float* x  = (const float*)d_in[0];   // [B, S, D]
    const float* Wg = (const float*)d_in[1];   // [D+H, 3H]
    const float* bg = (const float*)d_in[2];   // [3H]
    const float* Wc = (const float*)d_in[3];   // [H, O]
    const float* bc = (const float*)d_in[4];   // [O]
    float* out = (float*)d_out;                // [B, S, O]

    // Workspace layout:
    //   hs  : [B, S, H] bf16              = 67,108,864 B
    //   h0,h1 : [B, H] fp32 ping-pong     =    524,288 B
    //   Gx  : [CH, B, 3H] fp32 chunk      = CH * 786,432 B
    char* ws = (char*)d_ws;
    __hip_bfloat16* hs = (__hip_bfloat16*)ws;
    float* h0 = (float*)(ws + (size_t)BB * SS * HH * 2);
    float* h1 = h0 + BB * HH;
    float* Gx = h1 + BB * HH;

    size_t fixed = (size_t)BB * SS * HH * 2 + 2 * (size_t)BB * HH * 4;
    int CH = 512;
    while (CH > 2 && fixed + (size_t)CH * BB * TH3 * 4 > ws_size) CH >>= 1;

    hipMemsetAsync(h0, 0, (size_t)BB * HH * sizeof(float), stream);

    float* hc = h0;
    float* hn = h1;
    for (int s0 = 0; s0 < SS; s0 += CH) {
        dim3 g(TH3 / BN, (CH * BB) / BM);
        gx_gemm<<<g, 256, 0, stream>>>(x, Wg, bg, Gx, s0);
        for (int tt = 0; tt < CH; ++tt) {
            int t = s0 + tt;
            gru_step<<<HH / NT, 256, 0, stream>>>(
                Wg, Gx + (size_t)tt * BB * TH3, hc, hn, hs, t);
            float* tmp = hc; hc = hn; hn = tmp;
        }
    }

    {
        dim3 g2(HH / BN, (BB * SS) / BM);
        out_gemm<<<g2, 256, 0, stream>>>(hs, Wc, bc, out);
    }
}

// Round 3
// 20688.718 us; speedup vs baseline: 1.5219x; 1.5219x over previous
//
#include <hip/hip_runtime.h>
#include <hip/hip_bf16.h>
#include <stdint.h>

// Problem constants: B=64, S=512, D=1024, H=1024, O=1024
#define BB   64
#define SS   512
#define DD   1024
#define HH   1024
#define TH3  3072   // 3*H

using frag8 = __attribute__((ext_vector_type(8))) short;   // 8 bf16
using f32x4 = __attribute__((ext_vector_type(4))) float;

__device__ __forceinline__ void split_bf16(float v, short& hi, short& lo) {
    uint32_t u = __float_as_uint(v);
    uint32_t uh = u & 0xFFFF0000u;          // truncate to bf16
    float fl = v - __uint_as_float(uh);     // exact residual
    hi = (short)(uh >> 16);
    lo = (short)(__float_as_uint(fl) >> 16);
}

__device__ __forceinline__ float bf2f(unsigned short u) {
    union { uint32_t i; float f; } v;
    v.i = ((uint32_t)u) << 16;
    return v.f;
}

// ---------------------------------------------------------------------------
// W pre-transform: Wg [2048, 3072] fp32 -> Wt_hi/Wt_lo bf16 in MFMA B-fragment
// order. Fragment f = (jb*3 + g)*64 + kt covers k = kt*32 + quad*8 + j,
// n(col) = g*1024 + jb*16 + (lane&15). Stored as Wt[f*512 + lane*8 + j].
// ---------------------------------------------------------------------------
__global__ __launch_bounds__(256) void prep_w(
    const float* __restrict__ Wg, short* __restrict__ Wt_hi,
    short* __restrict__ Wt_lo)
{
    int idx = blockIdx.x * 256 + threadIdx.x;   // 0 .. 786431
    int lane = idx & 63;
    int f = idx >> 6;            // 0..12287
    int kt = f & 63;
    int fg = f >> 6;
    int g = fg % 3;
    int jb = fg / 3;
    int krow = kt * 32 + (lane >> 4) * 8;
    int col = g * HH + jb * 16 + (lane & 15);
    size_t dst = (size_t)f * 512 + (size_t)lane * 8;
#pragma unroll
    for (int j = 0; j < 8; ++j) {
        float v = Wg[(size_t)(krow + j) * TH3 + col];
        short hi, lo;
        split_bf16(v, hi, lo);
        Wt_hi[dst + j] = hi;
        Wt_lo[dst + j] = lo;
    }
}

// ---------------------------------------------------------------------------
// One GRU step via MFMA. Grid = 64 blocks (jb = 16 H-cols), 256 threads
// (4 waves; wave w owns batch rows w*16..w*16+15, all 3 gate n-tiles).
// gates = [x_t, h] @ Wg + bg with split-bf16 (hi+lo) x3 MFMA accumulation.
// ---------------------------------------------------------------------------
__global__ __launch_bounds__(256) void gru_step_mfma(
    const short* __restrict__ Wt_hi, const short* __restrict__ Wt_lo,
    const float* __restrict__ x,        // [B, S, D] fp32
    const float* __restrict__ bg,       // [3H]
    const float* __restrict__ h_f,      // [B, H] fp32 (current)
    const short* __restrict__ h_hi,     // [B, H] bf16 hi (current)
    const short* __restrict__ h_lo,     // [B, H] bf16 lo (current)
    float* __restrict__ hn_f,           // [B, H] fp32 (next)
    short* __restrict__ hn_hi, short* __restrict__ hn_lo,
    __hip_bfloat16* __restrict__ hs,    // [B, S, H] bf16 history
    int t)
{
    const int tid = threadIdx.x;
    const int lane = tid & 63;
    const int w = tid >> 6;
    const int m0 = w * 16;
    const int jb = blockIdx.x;

    const int mrow = m0 + (lane & 15);     // batch row for A fragment
    const int kq = (lane >> 4) * 8;        // quad k-offset

    f32x4 accr = {0.f, 0.f, 0.f, 0.f};
    f32x4 accz = {0.f, 0.f, 0.f, 0.f};
    f32x4 accn = {0.f, 0.f, 0.f, 0.f};

    const size_t fbase = (size_t)jb * 3 * 64;   // fragment index base

    // ---- phase 1: x contribution (W rows 0..1023, ktG = 0..31) ----
    const float* xrow = x + ((size_t)mrow * SS + t) * DD;
    for (int kt = 0; kt < 32; ++kt) {
        const float* xp = xrow + kt * 32 + kq;
        float xv[8];
        *(float4*)&xv[0] = *(const float4*)xp;
        *(float4*)&xv[4] = *(const float4*)(xp + 4);
        frag8 a_hi, a_lo;
#pragma unroll
        for (int j = 0; j < 8; ++j) {
            short hi, lo;
            split_bf16(xv[j], hi, lo);
            a_hi[j] = hi;
            a_lo[j] = lo;
        }
#pragma unroll
        for (int g = 0; g < 3; ++g) {
            size_t base = (fbase + (size_t)g * 64 + kt) * 512 + (size_t)lane * 8;
            frag8 b_hi = *(const frag8*)(Wt_hi + base);
            frag8 b_lo = *(const frag8*)(Wt_lo + base);
            f32x4 acc = (g == 0) ? accr : (g == 1) ? accz : accn;
            acc = __builtin_amdgcn_mfma_f32_16x16x32_bf16(a_hi, b_hi, acc, 0, 0, 0);
            acc = __builtin_amdgcn_mfma_f32_16x16x32_bf16(a_hi, b_lo, acc, 0, 0, 0);
            acc = __builtin_amdgcn_mfma_f32_16x16x32_bf16(a_lo, b_hi, acc, 0, 0, 0);
            if (g == 0) accr = acc; else if (g == 1) accz = acc; else accn = acc;
        }
    }

    // ---- phase 2: h contribution (W rows 1024..2047, ktG = 32..63) ----
    const short* hrh = h_hi + (size_t)mrow * HH;
    const short* hrl = h_lo + (size_t)mrow * HH;
    for (int kt = 0; kt < 32; ++kt) {
        frag8 a_hi = *(const frag8*)(hrh + kt * 32 + kq);
        frag8 a_lo = *(const frag8*)(hrl + kt * 32 + kq);
#pragma unroll
        for (int g = 0; g < 3; ++g) {
            size_t base = (fbase + (size_t)g * 64 + 32 + kt) * 512 + (size_t)lane * 8;
            frag8 b_hi = *(const frag8*)(Wt_hi + base);
            frag8 b_lo = *(const frag8*)(Wt_lo + base);
            f32x4 acc = (g == 0) ? accr : (g == 1) ? accz : accn;
            acc = __builtin_amdgcn_mfma_f32_16x16x32_bf16(a_hi, b_hi, acc, 0, 0, 0);
            acc = __builtin_amdgcn_mfma_f32_16x16x32_bf16(a_hi, b_lo, acc, 0, 0, 0);
            acc = __builtin_amdgcn_mfma_f32_16x16x32_bf16(a_lo, b_hi, acc, 0, 0, 0);
            if (g == 0) accr = acc; else if (g == 1) accz = acc; else accn = acc;
        }
    }

    // ---- epilogue: C layout col=lane&15, row=quad*4+reg ----
    const int col = jb * 16 + (lane & 15);
    const int rbase = m0 + (lane >> 4) * 4;
    const float b_r = bg[col];
    const float b_z = bg[HH + col];
    const float b_n = bg[2 * HH + col];
#pragma unroll
    for (int reg = 0; reg < 4; ++reg) {
        int m = rbase + reg;
        float hold = h_f[(size_t)m * HH + col];
        float rg = accr[reg] + b_r;
        float zg = accz[reg] + b_z;
        float ng = accn[reg] + b_n;
        float r = 1.f / (1.f + __expf(-rg));
        float z = 1.f / (1.f + __expf(-zg));
        float na = ng + r * hold;
        float n = 1.f - 2.f / (1.f + __expf(2.f * na));   // tanh(na)
        float hn = (1.f - z) * n + z * hold;
        hn_f[(size_t)m * HH + col] = hn;
        short hi, lo;
        split_bf16(hn, hi, lo);
        hn_hi[(size_t)m * HH + col] = hi;
        hn_lo[(size_t)m * HH + col] = lo;
        hs[((size_t)m * SS + t) * HH + col] = __float2bfloat16(hn);
    }
}

// ---------------------------------------------------------------------------
// Output GEMM: out[B*S, O] = hs_bf16[B*S, H] @ Wc[H, O] + bc  (fp32 vector)
// ---------------------------------------------------------------------------
#define BM 128
#define BN 128
#define BK 8

__global__ __launch_bounds__(256) void out_gemm(
    const __hip_bfloat16* __restrict__ A, const float* __restrict__ Bm,
    const float* __restrict__ bias, float* __restrict__ C)
{
    __shared__ float As[BK][BM + 4];
    __shared__ float Bs[BK][BN + 4];

    const int tid = threadIdx.x;
    const int bx = blockIdx.x;
    const int by = blockIdx.y;

    const int arow = tid >> 1;
    const int acol = (tid & 1) * 4;
    const int brow = tid >> 5;
    const int bcol = (tid & 31) * 4;

    const int tx8 = (tid & 15) * 8;
    const int ty8 = (tid >> 4) * 8;

    float acc[8][8];
#pragma unroll
    for (int i = 0; i < 8; ++i)
#pragma unroll
        for (int j = 0; j < 8; ++j) acc[i][j] = 0.f;

    const unsigned short* Aptr =
        (const unsigned short*)A + (size_t)(by * BM + arow) * HH + acol;
    const float* Bptr = Bm + (size_t)brow * HH + bx * BN + bcol;

    for (int k0 = 0; k0 < HH; k0 += BK) {
        ushort4 au = *(const ushort4*)Aptr;
        float4 bv = *(const float4*)Bptr;
        As[acol + 0][arow] = bf2f(au.x);
        As[acol + 1][arow] = bf2f(au.y);
        As[acol + 2][arow] = bf2f(au.z);
        As[acol + 3][arow] = bf2f(au.w);
        *(float4*)&Bs[brow][bcol] = bv;
        __syncthreads();

#pragma unroll
        for (int k = 0; k < BK; ++k) {
            float a[8], bvv[8];
            *(float4*)&a[0] = *(const float4*)&As[k][ty8];
            *(float4*)&a[4] = *(const float4*)&As[k][ty8 + 4];
            *(float4*)&bvv[0] = *(const float4*)&Bs[k][tx8];
            *(float4*)&bvv[4] = *(const float4*)&Bs[k][tx8 + 4];
#pragma unroll
            for (int i = 0; i < 8; ++i)
#pragma unroll
                for (int j = 0; j < 8; ++j)
                    acc[i][j] += a[i] * bvv[j];
        }
        __syncthreads();
        Aptr += BK;
        Bptr += (size_t)BK * HH;
    }

    float bv8[8];
#pragma unroll
    for (int j = 0; j < 8; ++j) bv8[j] = bias[bx * BN + tx8 + j];

#pragma unroll
    for (int i = 0; i < 8; ++i) {
        float* cptr = C + (size_t)(by * BM + ty8 + i) * HH + bx * BN + tx8;
        float4 v0, v1;
        v0.x = acc[i][0] + bv8[0];
        v0.y = acc[i][1] + bv8[1];
        v0.z = acc[i][2] + bv8[2];
        v0.w = acc[i][3] + bv8[3];
        v1.x = acc[i][4] + bv8[4];
        v1.y = acc[i][5] + bv8[5];
        v1.z = acc[i][6] + bv8[6];
        v1.w = acc[i][7] + bv8[7];
        *(float4*)cptr = v0;
        *(float4*)(cptr + 4) = v1;
    }
}

// ---------------------------------------------------------------------------
extern "C" void kernel_launch(void* const* d_in, const int* in_sizes, int n_in,
                              void* d_out, int out_size, void* d_ws, size_t ws_size,
                              hipStream_t stream) {
    const float* x  = (const float*)d_in[0];   // [B, S, D]
    const float* Wg = (const float*)d_in[1];   // [D+H, 3H]
    const float* bg = (const float*)d_in[2];   // [3H]
    const float* Wc = (const float*)d_in[3];   // [H, O]
    const float* bc = (const float*)d_in[4];   // [O]
    float* out = (float*)d_out;                // [B, S, O]

    // Workspace layout (93.3 MB total):
    //   hs    : [B,S,H] bf16                       67,108,864 B
    //   Wt_hi : [2048*3072] bf16 fragment order    12,582,912 B
    //   Wt_lo : same                               12,582,912 B
    //   2 x state set {h fp32, h_hi bf16, h_lo bf16} = 2 x 524,288 B
    char* ws = (char*)d_ws;
    __hip_bfloat16* hs = (__hip_bfloat16*)ws;
    short* Wt_hi = (short*)(ws + 67108864);
    short* Wt_lo = (short*)(ws + 67108864 + 12582912);
    char* state = ws + 67108864 + 2 * 12582912;
    // state set p (p=0,1): hf at +0 (256KB), hhi at +256KB (128KB), hlo at +384KB
    const size_t SET = 524288;

    float* hf[2];  short* hhi[2]; short* hlo[2];
    for (int p = 0; p < 2; ++p) {
        hf[p]  = (float*)(state + p * SET);
        hhi[p] = (short*)(state + p * SET + 262144);
        hlo[p] = (short*)(state + p * SET + 393216);
    }

    // zero the t=0 state set (fp32 h + hi + lo contiguous)
    hipMemsetAsync(state, 0, SET, stream);

    prep_w<<<3072, 256, 0, stream>>>(Wg, Wt_hi, Wt_lo);

    for (int t = 0; t < SS; ++t) {
        int c = t & 1, n = c ^ 1;
        gru_step_mfma<<<64, 256, 0, stream>>>(
            Wt_hi, Wt_lo, x, bg,
            hf[c], hhi[c], hlo[c],
            hf[n], hhi[n], hlo[n],
            hs, t);
    }

    {
        dim3 g2(HH / BN, (BB * SS) / BM);
        out_gemm<<<g2, 256, 0, stream>>>(hs, Wc, bc, out);
    }
}